// Round 3
// baseline (699.097 us; speedup 1.0000x reference)
//
#include <hip/hip_runtime.h>
#include <math.h>

// Problem constants
#define BB   16
#define CC   256
#define HW   1024          // 32*32
#define NN   16384         // BB*HW tokens
#define DD   256           // dim
#define KK   8192          // codes
#define ZQ_SIZE 4194304    // 16*256*1024
#define MARGIN 0.017f      // rigorous bf16-score error envelope (bound 0.0156)
#define PCAP (1 << 20)     // candidate-pair list capacity

typedef __attribute__((ext_vector_type(8))) short short8;  // 8 bf16 (4 VGPRs)
typedef __attribute__((ext_vector_type(4))) float f32x4;

static __device__ inline unsigned short f2bf(float x) {
    unsigned int u = __float_as_uint(x);
    unsigned int r = (u + 0x7fff + ((u >> 16) & 1)) >> 16;   // RNE
    return (unsigned short)r;
}

// ---------------------------------------------------------------------------
// Kernel 1: wsq[k] = sum_d W[k][d]^2 (fp32). One wave per row, 4 rows/block.
__global__ __launch_bounds__(256) void wsq_kernel(const float* __restrict__ W,
                                                  float* __restrict__ wsq) {
    const int lane = threadIdx.x & 63;
    const int k = blockIdx.x * 4 + (threadIdx.x >> 6);
    float4 v = *(const float4*)(W + (size_t)k * DD + lane * 4);
    float s = v.x * v.x + v.y * v.y + v.z * v.z + v.w * v.w;
    #pragma unroll
    for (int off = 32; off; off >>= 1) s += __shfl_down(s, off);
    if (lane == 0) wsq[k] = s;
}

// ---------------------------------------------------------------------------
// Kernel 2: transpose + l2-normalize; emits fp32 zn[n][d], znsq[n], and the
// bf16 tiled blob zb (exact LDS image for the MFMA stage).
__global__ __launch_bounds__(256) void normalize_kernel(const float* __restrict__ z,
                                                        float* __restrict__ zn,
                                                        float* __restrict__ znsq,
                                                        unsigned short* __restrict__ zb) {
    __shared__ float tile[64][257];
    __shared__ float s_nrm[64];
    const int t   = threadIdx.x;
    const int b   = blockIdx.x >> 4;
    const int hw0 = (blockIdx.x & 15) * 64;

    #pragma unroll 8
    for (int cg = 0; cg < 64; ++cg) {
        int c  = cg * 4 + (t >> 6);
        int hw = t & 63;
        tile[hw][c] = z[((size_t)(b * CC + c) << 10) + hw0 + hw];
    }
    __syncthreads();
    if (t < 64) {
        float s = 0.f;
        #pragma unroll 8
        for (int c = 0; c < 256; ++c) { float v = tile[t][c]; s += v * v; }
        float nrm = sqrtf(s);
        nrm = fmaxf(nrm, 1e-12f);
        s_nrm[t] = nrm;
        znsq[(size_t)b * HW + hw0 + t] = s / (nrm * nrm);
    }
    __syncthreads();
    const int n0 = b * HW + hw0;           // multiple of 64
    for (int r = 0; r < 64; ++r) {
        zn[(size_t)(n0 + r) * DD + t] = tile[r][t] / s_nrm[r];
    }
    const int r    = t & 63;
    const int mt   = n0 >> 7;
    const int rg   = (n0 & 127) + r;
    const float nrm = s_nrm[r];
    #pragma unroll
    for (int loop = 0; loop < 8; ++loop) {
        int comb = loop * 4 + (t >> 6);    // 0..31
        int dc = comb >> 3, c = comb & 7;
        int d0 = dc * 64 + c * 8;
        uint4 out;
        out.x = (unsigned int)f2bf(tile[r][d0 + 0] / nrm) | ((unsigned int)f2bf(tile[r][d0 + 1] / nrm) << 16);
        out.y = (unsigned int)f2bf(tile[r][d0 + 2] / nrm) | ((unsigned int)f2bf(tile[r][d0 + 3] / nrm) << 16);
        out.z = (unsigned int)f2bf(tile[r][d0 + 4] / nrm) | ((unsigned int)f2bf(tile[r][d0 + 5] / nrm) << 16);
        out.w = (unsigned int)f2bf(tile[r][d0 + 6] / nrm) | ((unsigned int)f2bf(tile[r][d0 + 7] / nrm) << 16);
        *(uint4*)(zb + (size_t)(mt * 4 + dc) * 8192 + (size_t)(c * 128 + rg) * 8) = out;
    }
}

// ---------------------------------------------------------------------------
// Kernel 3: W -> bf16 tiled blob wb (same layout, k-tiles of 128 codes).
__global__ __launch_bounds__(256) void wb_convert_kernel(const float* __restrict__ W,
                                                         unsigned short* __restrict__ wb) {
    const int ch = blockIdx.x * 256 + threadIdx.x;     // chunk id, 0..262143
    const int c = (ch >> 7) & 7;
    const int r = ch & 127;
    const int kt = ch >> 12, dc = (ch >> 10) & 3;
    const int k = kt * 128 + r;
    const int d0 = dc * 64 + c * 8;
    const float4 v0 = *(const float4*)(W + (size_t)k * DD + d0);
    const float4 v1 = *(const float4*)(W + (size_t)k * DD + d0 + 4);
    uint4 out;
    out.x = (unsigned int)f2bf(v0.x) | ((unsigned int)f2bf(v0.y) << 16);
    out.y = (unsigned int)f2bf(v0.z) | ((unsigned int)f2bf(v0.w) << 16);
    out.z = (unsigned int)f2bf(v1.x) | ((unsigned int)f2bf(v1.y) << 16);
    out.w = (unsigned int)f2bf(v1.z) | ((unsigned int)f2bf(v1.w) << 16);
    *(uint4*)(wb + (size_t)ch * 8) = out;
}

// ---------------------------------------------------------------------------
// Kernel 4: MFMA scorer. Block = 128 tokens x 128 codes; writes per-token
// per-32-code-group max of t = 2*dot_bf16 - wsq[k]  -> cmax[n][256].
__global__ __launch_bounds__(256) void score_kernel(const unsigned short* __restrict__ zb,
                                                    const unsigned short* __restrict__ wb,
                                                    const float* __restrict__ wsqv,
                                                    float* __restrict__ cmax) {
    __shared__ unsigned short sA[8192];   // 16 KB
    __shared__ unsigned short sB[8192];   // 16 KB
    __shared__ float rowbuf[128][4];

    const int tid  = threadIdx.x;
    const int w    = tid >> 6;
    const int lane = tid & 63;
    const int wr   = w >> 1, wc = w & 1;
    const int q    = lane >> 4, c15 = lane & 15;
    const int kt   = blockIdx.x & 63;
    const int mt   = blockIdx.x >> 6;

    f32x4 acc[4][4];
    #pragma unroll
    for (int fi = 0; fi < 4; ++fi)
        #pragma unroll
        for (int fj = 0; fj < 4; ++fj)
            acc[fi][fj] = (f32x4){0.f, 0.f, 0.f, 0.f};

    for (int dc = 0; dc < 4; ++dc) {
        const unsigned short* gA = zb + (size_t)(mt * 4 + dc) * 8192;
        const unsigned short* gB = wb + (size_t)(kt * 4 + dc) * 8192;
        #pragma unroll
        for (int i = 0; i < 4; ++i) {
            int eo = ((w * 4 + i) << 9);
            __builtin_amdgcn_global_load_lds(
                (const __attribute__((address_space(1))) void*)(gA + eo + lane * 8),
                (__attribute__((address_space(3))) void*)(sA + eo), 16, 0, 0);
            __builtin_amdgcn_global_load_lds(
                (const __attribute__((address_space(1))) void*)(gB + eo + lane * 8),
                (__attribute__((address_space(3))) void*)(sB + eo), 16, 0, 0);
        }
        __syncthreads();
        #pragma unroll
        for (int ks = 0; ks < 2; ++ks) {
            short8 af[4], bfr[4];
            const int ca = (ks * 4 + q) * 128;
            #pragma unroll
            for (int f = 0; f < 4; ++f) {
                af[f]  = *(const short8*)(sA + (size_t)(ca + wr * 64 + f * 16 + c15) * 8);
                bfr[f] = *(const short8*)(sB + (size_t)(ca + wc * 64 + f * 16 + c15) * 8);
            }
            #pragma unroll
            for (int fi = 0; fi < 4; ++fi)
                #pragma unroll
                for (int fj = 0; fj < 4; ++fj)
                    acc[fi][fj] = __builtin_amdgcn_mfma_f32_16x16x32_bf16(
                        af[fi], bfr[fj], acc[fi][fj], 0, 0, 0);
        }
        __syncthreads();
    }

    float wsqc[4];
    #pragma unroll
    for (int fj = 0; fj < 4; ++fj)
        wsqc[fj] = wsqv[kt * 128 + wc * 64 + fj * 16 + c15];

    #pragma unroll
    for (int fi = 0; fi < 4; ++fi) {
        float vmx[2][4];
        #pragma unroll
        for (int fjp = 0; fjp < 2; ++fjp) {
            #pragma unroll
            for (int rg = 0; rg < 4; ++rg) {
                float a0 = 2.0f * acc[fi][2 * fjp][rg]     - wsqc[2 * fjp];
                float a1 = 2.0f * acc[fi][2 * fjp + 1][rg] - wsqc[2 * fjp + 1];
                float v = fmaxf(a0, a1);
                v = fmaxf(v, __shfl_xor(v, 1));
                v = fmaxf(v, __shfl_xor(v, 2));
                v = fmaxf(v, __shfl_xor(v, 4));
                v = fmaxf(v, __shfl_xor(v, 8));
                vmx[fjp][rg] = v;
            }
        }
        if (c15 < 4) {
            int row = wr * 64 + fi * 16 + q * 4 + c15;
            rowbuf[row][wc * 2 + 0] = vmx[0][c15];
            rowbuf[row][wc * 2 + 1] = vmx[1][c15];
        }
    }
    __syncthreads();
    {
        int row = tid >> 1, half = tid & 1;
        float2 v2 = make_float2(rowbuf[row][half * 2], rowbuf[row][half * 2 + 1]);
        *(float2*)(cmax + (size_t)(mt * 128 + row) * 256 + kt * 4 + half * 2) = v2;
    }
}

// ---------------------------------------------------------------------------
// Kernel 5: zero the pair counter.
__global__ void zero_kernel(int* __restrict__ pcnt) { *pcnt = 0; }

// ---------------------------------------------------------------------------
// Kernel 6: candidate build. One wave per token; appends (n,g) pairs and
// initializes the per-token packed-best cell + overflow flag.
__global__ __launch_bounds__(256) void cand_kernel(const float* __restrict__ cmax,
                                                   unsigned int* __restrict__ glist,
                                                   int* __restrict__ pcnt,
                                                   unsigned long long* __restrict__ packed,
                                                   int* __restrict__ nflag) {
    const int t = threadIdx.x, wv = t >> 6, lane = t & 63;
    const int n = blockIdx.x * 4 + wv;
    float4 c4 = *(const float4*)(cmax + (size_t)n * 256 + lane * 4);
    float lm = fmaxf(fmaxf(c4.x, c4.y), fmaxf(c4.z, c4.w));
    #pragma unroll
    for (int off = 1; off <= 32; off <<= 1) lm = fmaxf(lm, __shfl_xor(lm, off));
    const float thresh = lm - MARGIN;
    if (lane == 0) { packed[n] = 0ull; nflag[n] = 0; }
    float g4[4] = {c4.x, c4.y, c4.z, c4.w};
    #pragma unroll
    for (int j = 0; j < 4; ++j) {
        if (g4[j] >= thresh) {
            int pos = atomicAdd(pcnt, 1);
            if (pos < PCAP) glist[pos] = ((unsigned int)n << 8) | (unsigned int)(lane * 4 + j);
            else            nflag[n] = 1;
        }
    }
}

// ---------------------------------------------------------------------------
// Rescore helper: exact fp32 score, bit-identical chain to the R2 select path.
static __device__ inline unsigned long long score_key(const float* __restrict__ zn,
                                                      const float* __restrict__ W,
                                                      const float* __restrict__ wsqv,
                                                      float zsq, int n, int k, int part) {
    const float4* wrp = (const float4*)(W + (size_t)k * DD + part * 128);
    const float4* zrp = (const float4*)(zn + (size_t)n * DD + part * 128);
    float d = 0.f;
    #pragma unroll
    for (int jj = 0; jj < 32; ++jj) {
        float4 a = zrp[jj], b = wrp[jj];
        d += a.x * b.x + a.y * b.y + a.z * b.z + a.w * b.w;
    }
    d += __shfl_xor(d, 1);
    float s = (-zsq - wsqv[k]) + 2.0f * d;
    unsigned int bits = __float_as_uint(s);
    unsigned int o = (bits & 0x80000000u) ? ~bits : (bits | 0x80000000u);
    return ((unsigned long long)o << 32) | (unsigned int)(~k);
}

// ---------------------------------------------------------------------------
// Kernel 7: pair rescore. Waves grid-stride the pair list; one atomicMax/pair.
__global__ __launch_bounds__(256) void rescore_kernel(const float* __restrict__ zn,
                                                      const float* __restrict__ W,
                                                      const float* __restrict__ wsqv,
                                                      const float* __restrict__ znsq,
                                                      const unsigned int* __restrict__ glist,
                                                      const int* __restrict__ pcnt,
                                                      unsigned long long* __restrict__ packed) {
    const int t = threadIdx.x, wv = t >> 6, lane = t & 63;
    const int code = lane >> 1, part = lane & 1;
    int total = *pcnt; if (total > PCAP) total = PCAP;
    const int nw = gridDim.x * 4;
    for (int i = blockIdx.x * 4 + wv; i < total; i += nw) {
        unsigned int p = glist[i];
        int n = (int)(p >> 8), g = (int)(p & 255u);
        int k = g * 32 + code;
        unsigned long long key = score_key(zn, W, wsqv, znsq[n], n, k, part);
        #pragma unroll
        for (int off = 1; off <= 32; off <<= 1) {
            unsigned long long ok = __shfl_xor(key, off);
            if (ok > key) key = ok;
        }
        if (lane == 0) atomicMax(packed + n, key);
    }
}

// ---------------------------------------------------------------------------
// Kernel 8: fullscan fallback for overflow-flagged tokens (normally no-op).
__global__ __launch_bounds__(256) void fullscan_kernel(const float* __restrict__ zn,
                                                       const float* __restrict__ W,
                                                       const float* __restrict__ wsqv,
                                                       const float* __restrict__ znsq,
                                                       const int* __restrict__ nflag,
                                                       unsigned long long* __restrict__ packed) {
    const int t = threadIdx.x, wv = t >> 6, lane = t & 63;
    const int code = lane >> 1, part = lane & 1;
    for (int n = blockIdx.x * 4 + wv; n < NN; n += gridDim.x * 4) {
        if (!nflag[n]) continue;
        float zsq = znsq[n];
        unsigned long long best = 0ull;
        for (int g = 0; g < 256; ++g) {
            unsigned long long key = score_key(zn, W, wsqv, zsq, n, g * 32 + code, part);
            if (key > best) best = key;
        }
        #pragma unroll
        for (int off = 1; off <= 32; off <<= 1) {
            unsigned long long ok = __shfl_xor(best, off);
            if (ok > best) best = ok;
        }
        if (lane == 0) atomicMax(packed + n, best);
    }
}

// ---------------------------------------------------------------------------
// Kernel 9: decode packed best -> idx outputs + loss partials.
__global__ __launch_bounds__(256) void finalize_kernel(const unsigned long long* __restrict__ packed,
                                                       int* __restrict__ bestk,
                                                       float* __restrict__ idxf,
                                                       float* __restrict__ partials) {
    __shared__ float wsum[4];
    const int t = threadIdx.x;
    const int n = blockIdx.x * 256 + t;
    unsigned long long key = packed[n];
    int k = (int)((~(unsigned int)key) & 0x3FFFu);
    unsigned int o = (unsigned int)(key >> 32);
    unsigned int bits = (o & 0x80000000u) ? (o & 0x7FFFFFFFu) : ~o;
    float s = __uint_as_float(bits);
    bestk[n] = k;
    idxf[n]  = (float)k;
    float c = -s;
    #pragma unroll
    for (int off = 32; off; off >>= 1) c += __shfl_down(c, off);
    if ((t & 63) == 0) wsum[t >> 6] = c;
    __syncthreads();
    if (t == 0) partials[blockIdx.x] = wsum[0] + wsum[1] + wsum[2] + wsum[3];
}

// ---------------------------------------------------------------------------
// Kernel 10: z_q gather, coalesced over hw.
__global__ __launch_bounds__(256) void gather_kernel(const float* __restrict__ W,
                                                     const int* __restrict__ bestk,
                                                     float* __restrict__ zq) {
    __shared__ int sbk[64];
    const int t   = threadIdx.x;
    const int b   = blockIdx.x >> 4;
    const int hw0 = (blockIdx.x & 15) * 64;
    if (t < 64) sbk[t] = bestk[b * HW + hw0 + t];
    __syncthreads();
    const int hw  = t & 63;
    const int c0  = (t >> 6) * 4;
    const int row = sbk[hw];
    #pragma unroll
    for (int cg = 0; cg < 16; ++cg) {
        int c = cg * 16 + c0;
        float4 v = *(const float4*)(W + (size_t)row * DD + c);
        size_t base = ((size_t)(b * CC + c) << 10) + hw0 + hw;
        zq[base]        = v.x;
        zq[base + 1024] = v.y;
        zq[base + 2048] = v.z;
        zq[base + 3072] = v.w;
    }
}

// ---------------------------------------------------------------------------
// Kernel 11: final loss = BETA * sum(64 partials) / (N*D)
__global__ __launch_bounds__(64) void loss_final_kernel(const float* __restrict__ partials,
                                                        float* __restrict__ out_loss) {
    const int t = threadIdx.x;
    float v = partials[t];
    #pragma unroll
    for (int off = 32; off; off >>= 1) v += __shfl_down(v, off);
    if (t == 0) *out_loss = 0.25f * (v / (float)ZQ_SIZE);
}

// ---------------------------------------------------------------------------
extern "C" void kernel_launch(void* const* d_in, const int* in_sizes, int n_in,
                              void* d_out, int out_size, void* d_ws, size_t ws_size,
                              hipStream_t stream) {
    const float* z = (const float*)d_in[0];   // [16,256,32,32]
    const float* W = (const float*)d_in[1];   // [8192,256]

    float* out   = (float*)d_out;
    float* zq    = out;                 // 4194304
    float* loss  = out + ZQ_SIZE;       // 1
    float* idxf  = out + ZQ_SIZE + 1;   // 16384 (idx as float)

    float* ws       = (float*)d_ws;
    float* zn       = ws;                         // 4194304 f   (16 MB)
    float* znsq     = zn + (size_t)NN * DD;       // 16384 f
    float* wsqv     = znsq + NN;                  // 8192 f
    int*   bestk    = (int*)(wsqv + KK);          // 16384 i
    float* partials = (float*)(bestk + NN);       // 64 f (pad 256)
    unsigned short* zb = (unsigned short*)(partials + 256);   // 8 MB
    unsigned short* wb = zb + (size_t)NN * DD;                // 4 MB
    float* cmax     = (float*)(wb + (size_t)KK * DD);         // 16 MB
    unsigned int* glist = (unsigned int*)(cmax + (size_t)NN * 256); // 4 MB
    unsigned long long* packed = (unsigned long long*)(glist + PCAP); // 128 KB
    int* pcnt  = (int*)(packed + NN);             // 1 (pad 64)
    int* nflag = pcnt + 64;                       // 16384 i

    wsq_kernel       <<<KK / 4, 256, 0, stream>>>(W, wsqv);
    normalize_kernel <<<BB * 16, 256, 0, stream>>>(z, zn, znsq, zb);
    wb_convert_kernel<<<KK * DD / 8 / 256, 256, 0, stream>>>(W, wb);
    score_kernel     <<<(NN / 128) * (KK / 128), 256, 0, stream>>>(zb, wb, wsqv, cmax);
    zero_kernel      <<<1, 1, 0, stream>>>(pcnt);
    cand_kernel      <<<NN / 4, 256, 0, stream>>>(cmax, glist, pcnt, packed, nflag);
    rescore_kernel   <<<2048, 256, 0, stream>>>(zn, W, wsqv, znsq, glist, pcnt, packed);
    fullscan_kernel  <<<64, 256, 0, stream>>>(zn, W, wsqv, znsq, nflag, packed);
    finalize_kernel  <<<NN / 256, 256, 0, stream>>>(packed, bestk, idxf, partials);
    gather_kernel    <<<BB * 16, 256, 0, stream>>>(W, bestk, zq);
    loss_final_kernel<<<1, 64, 0, stream>>>(partials, loss);
}

// Round 4
// 291.097 us; speedup vs baseline: 2.4016x; 2.4016x over previous
//
#include <hip/hip_runtime.h>
#include <math.h>

// Problem constants
#define BB   16
#define CC   256
#define HW   1024          // 32*32
#define NN   16384         // BB*HW tokens
#define DD   256           // dim
#define KK   8192          // codes
#define ZQ_SIZE 4194304    // 16*256*1024
#define MARGIN 0.017f      // rigorous bf16-score error envelope (bound 0.0156)
#define GCAP 8192          // per-group candidate-token capacity (overflow -> fullscan)

typedef __attribute__((ext_vector_type(8))) short short8;  // 8 bf16 (4 VGPRs)
typedef __attribute__((ext_vector_type(4))) float f32x4;

static __device__ inline unsigned short f2bf(float x) {
    unsigned int u = __float_as_uint(x);
    unsigned int r = (u + 0x7fff + ((u >> 16) & 1)) >> 16;   // RNE
    return (unsigned short)r;
}

static __device__ inline unsigned long long pack_key(float s, int k) {
    unsigned int bits = __float_as_uint(s);
    unsigned int o = (bits & 0x80000000u) ? ~bits : (bits | 0x80000000u);
    return ((unsigned long long)o << 32) | (unsigned int)(~k);
}

// ---------------------------------------------------------------------------
// Kernel 1: wsq[k] = sum_d W[k][d]^2 (fp32); block 0 also zeroes gcnt/oflow.
__global__ __launch_bounds__(256) void wsq_kernel(const float* __restrict__ W,
                                                  float* __restrict__ wsq,
                                                  int* __restrict__ gcnt,
                                                  int* __restrict__ oflow) {
    if (blockIdx.x == 0) {
        gcnt[threadIdx.x] = 0;
        if (threadIdx.x == 0) *oflow = 0;
    }
    const int lane = threadIdx.x & 63;
    const int k = blockIdx.x * 4 + (threadIdx.x >> 6);
    float4 v = *(const float4*)(W + (size_t)k * DD + lane * 4);
    float s = v.x * v.x + v.y * v.y + v.z * v.z + v.w * v.w;
    #pragma unroll
    for (int off = 32; off; off >>= 1) s += __shfl_down(s, off);
    if (lane == 0) wsq[k] = s;
}

// ---------------------------------------------------------------------------
// Kernel 2: transpose + l2-normalize; emits fp32 zn[n][d], znsq[n], and the
// bf16 tiled blob zb (exact LDS image for the MFMA stage).
__global__ __launch_bounds__(256) void normalize_kernel(const float* __restrict__ z,
                                                        float* __restrict__ zn,
                                                        float* __restrict__ znsq,
                                                        unsigned short* __restrict__ zb) {
    __shared__ float tile[64][257];
    __shared__ float s_nrm[64];
    const int t   = threadIdx.x;
    const int b   = blockIdx.x >> 4;
    const int hw0 = (blockIdx.x & 15) * 64;

    #pragma unroll 8
    for (int cg = 0; cg < 64; ++cg) {
        int c  = cg * 4 + (t >> 6);
        int hw = t & 63;
        tile[hw][c] = z[((size_t)(b * CC + c) << 10) + hw0 + hw];
    }
    __syncthreads();
    if (t < 64) {
        float s = 0.f;
        #pragma unroll 8
        for (int c = 0; c < 256; ++c) { float v = tile[t][c]; s += v * v; }
        float nrm = sqrtf(s);
        nrm = fmaxf(nrm, 1e-12f);
        s_nrm[t] = nrm;
        znsq[(size_t)b * HW + hw0 + t] = s / (nrm * nrm);
    }
    __syncthreads();
    const int n0 = b * HW + hw0;           // multiple of 64
    for (int r = 0; r < 64; ++r) {
        zn[(size_t)(n0 + r) * DD + t] = tile[r][t] / s_nrm[r];
    }
    const int r    = t & 63;
    const int mt   = n0 >> 7;
    const int rg   = (n0 & 127) + r;
    const float nrm = s_nrm[r];
    #pragma unroll
    for (int loop = 0; loop < 8; ++loop) {
        int comb = loop * 4 + (t >> 6);    // 0..31
        int dc = comb >> 3, c = comb & 7;
        int d0 = dc * 64 + c * 8;
        uint4 out;
        out.x = (unsigned int)f2bf(tile[r][d0 + 0] / nrm) | ((unsigned int)f2bf(tile[r][d0 + 1] / nrm) << 16);
        out.y = (unsigned int)f2bf(tile[r][d0 + 2] / nrm) | ((unsigned int)f2bf(tile[r][d0 + 3] / nrm) << 16);
        out.z = (unsigned int)f2bf(tile[r][d0 + 4] / nrm) | ((unsigned int)f2bf(tile[r][d0 + 5] / nrm) << 16);
        out.w = (unsigned int)f2bf(tile[r][d0 + 6] / nrm) | ((unsigned int)f2bf(tile[r][d0 + 7] / nrm) << 16);
        *(uint4*)(zb + (size_t)(mt * 4 + dc) * 8192 + (size_t)(c * 128 + rg) * 8) = out;
    }
}

// ---------------------------------------------------------------------------
// Kernel 3: W -> bf16 tiled blob wb (same layout, k-tiles of 128 codes).
__global__ __launch_bounds__(256) void wb_convert_kernel(const float* __restrict__ W,
                                                         unsigned short* __restrict__ wb) {
    const int ch = blockIdx.x * 256 + threadIdx.x;     // chunk id, 0..262143
    const int c = (ch >> 7) & 7;
    const int r = ch & 127;
    const int kt = ch >> 12, dc = (ch >> 10) & 3;
    const int k = kt * 128 + r;
    const int d0 = dc * 64 + c * 8;
    const float4 v0 = *(const float4*)(W + (size_t)k * DD + d0);
    const float4 v1 = *(const float4*)(W + (size_t)k * DD + d0 + 4);
    uint4 out;
    out.x = (unsigned int)f2bf(v0.x) | ((unsigned int)f2bf(v0.y) << 16);
    out.y = (unsigned int)f2bf(v0.z) | ((unsigned int)f2bf(v0.w) << 16);
    out.z = (unsigned int)f2bf(v1.x) | ((unsigned int)f2bf(v1.y) << 16);
    out.w = (unsigned int)f2bf(v1.z) | ((unsigned int)f2bf(v1.w) << 16);
    *(uint4*)(wb + (size_t)ch * 8) = out;
}

// ---------------------------------------------------------------------------
// Kernel 4: MFMA scorer. Block = 128 tokens x 128 codes; writes per-token
// per-32-code-group max of t = 2*dot_bf16 - wsq[k]  -> cmax[n][256].
__global__ __launch_bounds__(256) void score_kernel(const unsigned short* __restrict__ zb,
                                                    const unsigned short* __restrict__ wb,
                                                    const float* __restrict__ wsqv,
                                                    float* __restrict__ cmax) {
    __shared__ unsigned short sA[8192];   // 16 KB
    __shared__ unsigned short sB[8192];   // 16 KB
    __shared__ float rowbuf[128][4];

    const int tid  = threadIdx.x;
    const int w    = tid >> 6;
    const int lane = tid & 63;
    const int wr   = w >> 1, wc = w & 1;
    const int q    = lane >> 4, c15 = lane & 15;
    const int kt   = blockIdx.x & 63;
    const int mt   = blockIdx.x >> 6;

    f32x4 acc[4][4];
    #pragma unroll
    for (int fi = 0; fi < 4; ++fi)
        #pragma unroll
        for (int fj = 0; fj < 4; ++fj)
            acc[fi][fj] = (f32x4){0.f, 0.f, 0.f, 0.f};

    for (int dc = 0; dc < 4; ++dc) {
        const unsigned short* gA = zb + (size_t)(mt * 4 + dc) * 8192;
        const unsigned short* gB = wb + (size_t)(kt * 4 + dc) * 8192;
        #pragma unroll
        for (int i = 0; i < 4; ++i) {
            int eo = ((w * 4 + i) << 9);
            __builtin_amdgcn_global_load_lds(
                (const __attribute__((address_space(1))) void*)(gA + eo + lane * 8),
                (__attribute__((address_space(3))) void*)(sA + eo), 16, 0, 0);
            __builtin_amdgcn_global_load_lds(
                (const __attribute__((address_space(1))) void*)(gB + eo + lane * 8),
                (__attribute__((address_space(3))) void*)(sB + eo), 16, 0, 0);
        }
        __syncthreads();
        #pragma unroll
        for (int ks = 0; ks < 2; ++ks) {
            short8 af[4], bfr[4];
            const int ca = (ks * 4 + q) * 128;
            #pragma unroll
            for (int f = 0; f < 4; ++f) {
                af[f]  = *(const short8*)(sA + (size_t)(ca + wr * 64 + f * 16 + c15) * 8);
                bfr[f] = *(const short8*)(sB + (size_t)(ca + wc * 64 + f * 16 + c15) * 8);
            }
            #pragma unroll
            for (int fi = 0; fi < 4; ++fi)
                #pragma unroll
                for (int fj = 0; fj < 4; ++fj)
                    acc[fi][fj] = __builtin_amdgcn_mfma_f32_16x16x32_bf16(
                        af[fi], bfr[fj], acc[fi][fj], 0, 0, 0);
        }
        __syncthreads();
    }

    float wsqc[4];
    #pragma unroll
    for (int fj = 0; fj < 4; ++fj)
        wsqc[fj] = wsqv[kt * 128 + wc * 64 + fj * 16 + c15];

    #pragma unroll
    for (int fi = 0; fi < 4; ++fi) {
        float vmx[2][4];
        #pragma unroll
        for (int fjp = 0; fjp < 2; ++fjp) {
            #pragma unroll
            for (int rg = 0; rg < 4; ++rg) {
                float a0 = 2.0f * acc[fi][2 * fjp][rg]     - wsqc[2 * fjp];
                float a1 = 2.0f * acc[fi][2 * fjp + 1][rg] - wsqc[2 * fjp + 1];
                float v = fmaxf(a0, a1);
                v = fmaxf(v, __shfl_xor(v, 1));
                v = fmaxf(v, __shfl_xor(v, 2));
                v = fmaxf(v, __shfl_xor(v, 4));
                v = fmaxf(v, __shfl_xor(v, 8));
                vmx[fjp][rg] = v;
            }
        }
        if (c15 < 4) {
            int row = wr * 64 + fi * 16 + q * 4 + c15;
            rowbuf[row][wc * 2 + 0] = vmx[0][c15];
            rowbuf[row][wc * 2 + 1] = vmx[1][c15];
        }
    }
    __syncthreads();
    {
        int row = tid >> 1, half = tid & 1;
        float2 v2 = make_float2(rowbuf[row][half * 2], rowbuf[row][half * 2 + 1]);
        *(float2*)(cmax + (size_t)(mt * 128 + row) * 256 + kt * 4 + half * 2) = v2;
    }
}

// ---------------------------------------------------------------------------
// Kernel 5: candidate build, bucketed by group. One wave per token.
// Atomics spread over 256 per-group counters (64 distinct addrs per wave-op).
__global__ __launch_bounds__(256) void cand_kernel(const float* __restrict__ cmax,
                                                   unsigned int* __restrict__ gseg,
                                                   int* __restrict__ gcnt,
                                                   unsigned long long* __restrict__ packed,
                                                   int* __restrict__ nflag,
                                                   int* __restrict__ oflow) {
    const int t = threadIdx.x, wv = t >> 6, lane = t & 63;
    const int n = blockIdx.x * 4 + wv;
    float4 c4 = *(const float4*)(cmax + (size_t)n * 256 + lane * 4);
    float lm = fmaxf(fmaxf(c4.x, c4.y), fmaxf(c4.z, c4.w));
    #pragma unroll
    for (int off = 1; off <= 32; off <<= 1) lm = fmaxf(lm, __shfl_xor(lm, off));
    const float thresh = lm - MARGIN;
    if (lane == 0) { packed[n] = 0ull; nflag[n] = 0; }
    float g4[4] = {c4.x, c4.y, c4.z, c4.w};
    #pragma unroll
    for (int j = 0; j < 4; ++j) {
        int g = lane * 4 + j;
        if (g4[j] >= thresh) {
            int pos = atomicAdd(&gcnt[g], 1);
            if (pos < GCAP) gseg[(size_t)g * GCAP + pos] = (unsigned int)n;
            else { nflag[n] = 1; atomicAdd(oflow, 1); }
        }
    }
}

// ---------------------------------------------------------------------------
// Kernel 6: group-centric exact fp32 rescore. One block per group; W group
// (32 codes x 256 d = 32 KB) staged in LDS once; lane = code; 2 tokens/wave/iter.
__global__ __launch_bounds__(256) void rescore_kernel(const float* __restrict__ zn,
                                                      const float* __restrict__ W,
                                                      const float* __restrict__ wsqv,
                                                      const float* __restrict__ znsq,
                                                      const unsigned int* __restrict__ gseg,
                                                      const int* __restrict__ gcnt,
                                                      unsigned long long* __restrict__ packed) {
    __shared__ float sW[32 * 260];       // stride 260: 4-way (full-BW) reads
    __shared__ float znr[4][2][256];     // per-wave, per-half token rows

    const int t = threadIdx.x;
    const int g = blockIdx.x;
    int cnt = gcnt[g]; if (cnt > GCAP) cnt = GCAP;
    if (cnt == 0) return;

    {   // stage W group (contiguous 32 KB chunk of W)
        int c = t >> 3, i = t & 7;
        const float4* src = (const float4*)(W + (size_t)g * 8192 + c * 256 + i * 32);
        #pragma unroll
        for (int j = 0; j < 8; ++j)
            *(float4*)(sW + c * 260 + i * 32 + j * 4) = src[j];
    }
    __syncthreads();

    const int wv = t >> 6, lane = t & 63;
    const int h = lane >> 5, c = lane & 31;
    const int k = g * 32 + c;
    const float wq = wsqv[k];
    const float4* wrow = (const float4*)(sW + c * 260);

    for (int base = wv * 2; base < cnt; base += 8) {
        int idx = base + h; if (idx >= cnt) idx = base;
        int n = (int)gseg[(size_t)g * GCAP + idx];
        // stage token row (32 lanes of this half, 8 floats each)
        *(float4*)(&znr[wv][h][c * 8])     = *(const float4*)(zn + (size_t)n * DD + c * 8);
        *(float4*)(&znr[wv][h][c * 8 + 4]) = *(const float4*)(zn + (size_t)n * DD + c * 8 + 4);
        float d = 0.f;
        #pragma unroll
        for (int j = 0; j < 64; ++j) {
            float4 wv4 = wrow[j];
            float4 zv  = *(const float4*)(&znr[wv][h][j * 4]);
            d += wv4.x * zv.x + wv4.y * zv.y + wv4.z * zv.z + wv4.w * zv.w;
        }
        float s = (-znsq[n] - wq) + 2.0f * d;
        unsigned long long key = pack_key(s, k);
        #pragma unroll
        for (int off = 1; off <= 16; off <<= 1) {
            unsigned long long ok = __shfl_xor(key, off);
            if (ok > key) key = ok;
        }
        if (c == 0) atomicMax(packed + n, key);
    }
}

// ---------------------------------------------------------------------------
// Kernel 7: fullscan fallback for overflow-flagged tokens (early-exits when
// no overflow happened — the expected case).
__global__ __launch_bounds__(256) void fullscan_kernel(const float* __restrict__ zn,
                                                       const float* __restrict__ W,
                                                       const float* __restrict__ wsqv,
                                                       const float* __restrict__ znsq,
                                                       const int* __restrict__ nflag,
                                                       const int* __restrict__ oflow,
                                                       unsigned long long* __restrict__ packed) {
    if (*oflow == 0) return;
    const int t = threadIdx.x, wv = t >> 6, lane = t & 63;
    const int code = lane >> 1, part = lane & 1;
    for (int n = blockIdx.x * 4 + wv; n < NN; n += gridDim.x * 4) {
        if (!nflag[n]) continue;
        float zsq = znsq[n];
        unsigned long long best = 0ull;
        for (int gg = 0; gg < 256; ++gg) {
            int k = gg * 32 + code;
            const float4* wrp = (const float4*)(W + (size_t)k * DD + part * 128);
            const float4* zrp = (const float4*)(zn + (size_t)n * DD + part * 128);
            float d = 0.f;
            #pragma unroll
            for (int jj = 0; jj < 32; ++jj) {
                float4 a = zrp[jj], b = wrp[jj];
                d += a.x * b.x + a.y * b.y + a.z * b.z + a.w * b.w;
            }
            d += __shfl_xor(d, 1);
            unsigned long long key = pack_key((-zsq - wsqv[k]) + 2.0f * d, k);
            if (key > best) best = key;
        }
        #pragma unroll
        for (int off = 1; off <= 32; off <<= 1) {
            unsigned long long ok = __shfl_xor(best, off);
            if (ok > best) best = ok;
        }
        if (lane == 0) atomicMax(packed + n, best);
    }
}

// ---------------------------------------------------------------------------
// Kernel 8: decode packed best -> idx outputs + loss partials.
__global__ __launch_bounds__(256) void finalize_kernel(const unsigned long long* __restrict__ packed,
                                                       int* __restrict__ bestk,
                                                       float* __restrict__ idxf,
                                                       float* __restrict__ partials) {
    __shared__ float wsum[4];
    const int t = threadIdx.x;
    const int n = blockIdx.x * 256 + t;
    unsigned long long key = packed[n];
    int k = (int)((~(unsigned int)key) & 0x3FFFu);
    unsigned int o = (unsigned int)(key >> 32);
    unsigned int bits = (o & 0x80000000u) ? (o & 0x7FFFFFFFu) : ~o;
    float s = __uint_as_float(bits);
    bestk[n] = k;
    idxf[n]  = (float)k;
    float c = -s;
    #pragma unroll
    for (int off = 32; off; off >>= 1) c += __shfl_down(c, off);
    if ((t & 63) == 0) wsum[t >> 6] = c;
    __syncthreads();
    if (t == 0) partials[blockIdx.x] = wsum[0] + wsum[1] + wsum[2] + wsum[3];
}

// ---------------------------------------------------------------------------
// Kernel 9: z_q gather, coalesced over hw.
__global__ __launch_bounds__(256) void gather_kernel(const float* __restrict__ W,
                                                     const int* __restrict__ bestk,
                                                     float* __restrict__ zq) {
    __shared__ int sbk[64];
    const int t   = threadIdx.x;
    const int b   = blockIdx.x >> 4;
    const int hw0 = (blockIdx.x & 15) * 64;
    if (t < 64) sbk[t] = bestk[b * HW + hw0 + t];
    __syncthreads();
    const int hw  = t & 63;
    const int c0  = (t >> 6) * 4;
    const int row = sbk[hw];
    #pragma unroll
    for (int cg = 0; cg < 16; ++cg) {
        int c = cg * 16 + c0;
        float4 v = *(const float4*)(W + (size_t)row * DD + c);
        size_t base = ((size_t)(b * CC + c) << 10) + hw0 + hw;
        zq[base]        = v.x;
        zq[base + 1024] = v.y;
        zq[base + 2048] = v.z;
        zq[base + 3072] = v.w;
    }
}

// ---------------------------------------------------------------------------
// Kernel 10: final loss = BETA * sum(64 partials) / (N*D)
__global__ __launch_bounds__(64) void loss_final_kernel(const float* __restrict__ partials,
                                                        float* __restrict__ out_loss) {
    const int t = threadIdx.x;
    float v = partials[t];
    #pragma unroll
    for (int off = 32; off; off >>= 1) v += __shfl_down(v, off);
    if (t == 0) *out_loss = 0.25f * (v / (float)ZQ_SIZE);
}

// ---------------------------------------------------------------------------
extern "C" void kernel_launch(void* const* d_in, const int* in_sizes, int n_in,
                              void* d_out, int out_size, void* d_ws, size_t ws_size,
                              hipStream_t stream) {
    const float* z = (const float*)d_in[0];   // [16,256,32,32]
    const float* W = (const float*)d_in[1];   // [8192,256]

    float* out   = (float*)d_out;
    float* zq    = out;                 // 4194304
    float* loss  = out + ZQ_SIZE;       // 1
    float* idxf  = out + ZQ_SIZE + 1;   // 16384 (idx as float)

    float* ws       = (float*)d_ws;
    float* zn       = ws;                         // 16 MB
    float* znsq     = zn + (size_t)NN * DD;       // 16384 f
    float* wsqv     = znsq + NN;                  // 8192 f
    int*   bestk    = (int*)(wsqv + KK);          // 16384 i
    float* partials = (float*)(bestk + NN);       // 64 f (pad 256)
    int*   gcnt     = (int*)(partials + 256);     // 256 i
    int*   oflow    = gcnt + 256;                 // 1 (pad 64)
    int*   nflag    = oflow + 64;                 // 16384 i
    unsigned short* zb = (unsigned short*)(nflag + NN);       // 8 MB
    unsigned short* wb = zb + (size_t)NN * DD;                // 4 MB
    float* cmax     = (float*)(wb + (size_t)KK * DD);         // 16 MB
    unsigned int* gseg = (unsigned int*)(cmax + (size_t)NN * 256); // 256*8192*4 = 8 MB
    unsigned long long* packed = (unsigned long long*)(gseg + (size_t)256 * GCAP); // 128 KB

    wsq_kernel       <<<KK / 4, 256, 0, stream>>>(W, wsqv, gcnt, oflow);
    normalize_kernel <<<BB * 16, 256, 0, stream>>>(z, zn, znsq, zb);
    wb_convert_kernel<<<KK * DD / 8 / 256, 256, 0, stream>>>(W, wb);
    score_kernel     <<<(NN / 128) * (KK / 128), 256, 0, stream>>>(zb, wb, wsqv, cmax);
    cand_kernel      <<<NN / 4, 256, 0, stream>>>(cmax, gseg, gcnt, packed, nflag, oflow);
    rescore_kernel   <<<256, 256, 0, stream>>>(zn, W, wsqv, znsq, gseg, gcnt, packed);
    fullscan_kernel  <<<64, 256, 0, stream>>>(zn, W, wsqv, znsq, nflag, oflow, packed);
    finalize_kernel  <<<NN / 256, 256, 0, stream>>>(packed, bestk, idxf, partials);
    gather_kernel    <<<BB * 16, 256, 0, stream>>>(W, bestk, zq);
    loss_final_kernel<<<1, 64, 0, stream>>>(partials, loss);
}

// Round 7
// 290.235 us; speedup vs baseline: 2.4087x; 1.0030x over previous
//
#include <hip/hip_runtime.h>
#include <math.h>

// Problem constants
#define BB   16
#define CC   256
#define HW   1024          // 32*32
#define NN   16384         // BB*HW tokens
#define DD   256           // dim
#define KK   8192          // codes
#define ZQ_SIZE 4194304    // 16*256*1024
#define MARGIN 0.017f      // rigorous bf16-score error envelope (bound 0.0156)
#define GCAP 8192          // per-group candidate-token capacity (overflow -> fullscan)

typedef __attribute__((ext_vector_type(8))) short short8;  // 8 bf16 (4 VGPRs)
typedef __attribute__((ext_vector_type(4))) float f32x4;

static __device__ inline unsigned short f2bf(float x) {
    unsigned int u = __float_as_uint(x);
    unsigned int r = (u + 0x7fff + ((u >> 16) & 1)) >> 16;   // RNE
    return (unsigned short)r;
}

static __device__ inline unsigned long long pack_key(float s, int k) {
    unsigned int bits = __float_as_uint(s);
    unsigned int o = (bits & 0x80000000u) ? ~bits : (bits | 0x80000000u);
    return ((unsigned long long)o << 32) | (unsigned int)(~k);
}

// ---------------------------------------------------------------------------
// Kernel 1: wsq[k] = sum_d W[k][d]^2 — VERBATIM R4 chain (4-elem chunks +
// 64-lane tree). DO NOT CHANGE THE SUMMATION ORDER: the final argmax compare
// is a knife-edge fp32 tie for at least one token; this order is part of the
// passing contract (R5/R6 flipped it via a reordered wsq and failed).
// Block 0 also zeroes gcnt/oflow.
__global__ __launch_bounds__(256) void wsq_kernel(const float* __restrict__ W,
                                                  float* __restrict__ wsq,
                                                  int* __restrict__ gcnt,
                                                  int* __restrict__ oflow) {
    if (blockIdx.x == 0) {
        gcnt[threadIdx.x] = 0;
        if (threadIdx.x == 0) *oflow = 0;
    }
    const int lane = threadIdx.x & 63;
    const int k = blockIdx.x * 4 + (threadIdx.x >> 6);
    float4 v = *(const float4*)(W + (size_t)k * DD + lane * 4);
    float s = v.x * v.x + v.y * v.y + v.z * v.z + v.w * v.w;
    #pragma unroll
    for (int off = 32; off; off >>= 1) s += __shfl_down(s, off);
    if (lane == 0) wsq[k] = s;
}

// ---------------------------------------------------------------------------
// Kernel 2: transpose + l2-normalize; emits fp32 zn[n][d], znsq[n], and the
// bf16 tiled blob zb (exact LDS image for the MFMA stage).
__global__ __launch_bounds__(256) void normalize_kernel(const float* __restrict__ z,
                                                        float* __restrict__ zn,
                                                        float* __restrict__ znsq,
                                                        unsigned short* __restrict__ zb) {
    __shared__ float tile[64][257];
    __shared__ float s_nrm[64];
    const int t   = threadIdx.x;
    const int b   = blockIdx.x >> 4;
    const int hw0 = (blockIdx.x & 15) * 64;

    #pragma unroll 8
    for (int cg = 0; cg < 64; ++cg) {
        int c  = cg * 4 + (t >> 6);
        int hw = t & 63;
        tile[hw][c] = z[((size_t)(b * CC + c) << 10) + hw0 + hw];
    }
    __syncthreads();
    if (t < 64) {
        float s = 0.f;
        #pragma unroll 8
        for (int c = 0; c < 256; ++c) { float v = tile[t][c]; s += v * v; }
        float nrm = sqrtf(s);
        nrm = fmaxf(nrm, 1e-12f);
        s_nrm[t] = nrm;
        znsq[(size_t)b * HW + hw0 + t] = s / (nrm * nrm);
    }
    __syncthreads();
    const int n0 = b * HW + hw0;           // multiple of 64
    for (int r = 0; r < 64; ++r) {
        zn[(size_t)(n0 + r) * DD + t] = tile[r][t] / s_nrm[r];
    }
    const int r    = t & 63;
    const int mt   = n0 >> 7;
    const int rg   = (n0 & 127) + r;
    const float nrm = s_nrm[r];
    #pragma unroll
    for (int loop = 0; loop < 8; ++loop) {
        int comb = loop * 4 + (t >> 6);    // 0..31
        int dc = comb >> 3, c = comb & 7;
        int d0 = dc * 64 + c * 8;
        uint4 out;
        out.x = (unsigned int)f2bf(tile[r][d0 + 0] / nrm) | ((unsigned int)f2bf(tile[r][d0 + 1] / nrm) << 16);
        out.y = (unsigned int)f2bf(tile[r][d0 + 2] / nrm) | ((unsigned int)f2bf(tile[r][d0 + 3] / nrm) << 16);
        out.z = (unsigned int)f2bf(tile[r][d0 + 4] / nrm) | ((unsigned int)f2bf(tile[r][d0 + 5] / nrm) << 16);
        out.w = (unsigned int)f2bf(tile[r][d0 + 6] / nrm) | ((unsigned int)f2bf(tile[r][d0 + 7] / nrm) << 16);
        *(uint4*)(zb + (size_t)(mt * 4 + dc) * 8192 + (size_t)(c * 128 + rg) * 8) = out;
    }
}

// ---------------------------------------------------------------------------
// Kernel 3: W -> bf16 tiled blob wb — VERBATIM R4.
__global__ __launch_bounds__(256) void wb_convert_kernel(const float* __restrict__ W,
                                                         unsigned short* __restrict__ wb) {
    const int ch = blockIdx.x * 256 + threadIdx.x;     // chunk id, 0..262143
    const int c = (ch >> 7) & 7;
    const int r = ch & 127;
    const int kt = ch >> 12, dc = (ch >> 10) & 3;
    const int k = kt * 128 + r;
    const int d0 = dc * 64 + c * 8;
    const float4 v0 = *(const float4*)(W + (size_t)k * DD + d0);
    const float4 v1 = *(const float4*)(W + (size_t)k * DD + d0 + 4);
    uint4 out;
    out.x = (unsigned int)f2bf(v0.x) | ((unsigned int)f2bf(v0.y) << 16);
    out.y = (unsigned int)f2bf(v0.z) | ((unsigned int)f2bf(v0.w) << 16);
    out.z = (unsigned int)f2bf(v1.x) | ((unsigned int)f2bf(v1.y) << 16);
    out.w = (unsigned int)f2bf(v1.z) | ((unsigned int)f2bf(v1.w) << 16);
    *(uint4*)(wb + (size_t)ch * 8) = out;
}

// ---------------------------------------------------------------------------
// Kernel 4: MFMA scorer — VERBATIM R4 (untransposed; A=tokens, B=codes).
// Writes cmax[n][g] = per-token per-32-code-group max of 2*dot_bf16 - wsq[k].
__global__ __launch_bounds__(256) void score_kernel(const unsigned short* __restrict__ zb,
                                                    const unsigned short* __restrict__ wb,
                                                    const float* __restrict__ wsqv,
                                                    float* __restrict__ cmax) {
    __shared__ unsigned short sA[8192];   // 16 KB
    __shared__ unsigned short sB[8192];   // 16 KB
    __shared__ float rowbuf[128][4];

    const int tid  = threadIdx.x;
    const int w    = tid >> 6;
    const int lane = tid & 63;
    const int wr   = w >> 1, wc = w & 1;
    const int q    = lane >> 4, c15 = lane & 15;
    const int kt   = blockIdx.x & 63;
    const int mt   = blockIdx.x >> 6;

    f32x4 acc[4][4];
    #pragma unroll
    for (int fi = 0; fi < 4; ++fi)
        #pragma unroll
        for (int fj = 0; fj < 4; ++fj)
            acc[fi][fj] = (f32x4){0.f, 0.f, 0.f, 0.f};

    for (int dc = 0; dc < 4; ++dc) {
        const unsigned short* gA = zb + (size_t)(mt * 4 + dc) * 8192;
        const unsigned short* gB = wb + (size_t)(kt * 4 + dc) * 8192;
        #pragma unroll
        for (int i = 0; i < 4; ++i) {
            int eo = ((w * 4 + i) << 9);
            __builtin_amdgcn_global_load_lds(
                (const __attribute__((address_space(1))) void*)(gA + eo + lane * 8),
                (__attribute__((address_space(3))) void*)(sA + eo), 16, 0, 0);
            __builtin_amdgcn_global_load_lds(
                (const __attribute__((address_space(1))) void*)(gB + eo + lane * 8),
                (__attribute__((address_space(3))) void*)(sB + eo), 16, 0, 0);
        }
        __syncthreads();
        #pragma unroll
        for (int ks = 0; ks < 2; ++ks) {
            short8 af[4], bfr[4];
            const int ca = (ks * 4 + q) * 128;
            #pragma unroll
            for (int f = 0; f < 4; ++f) {
                af[f]  = *(const short8*)(sA + (size_t)(ca + wr * 64 + f * 16 + c15) * 8);
                bfr[f] = *(const short8*)(sB + (size_t)(ca + wc * 64 + f * 16 + c15) * 8);
            }
            #pragma unroll
            for (int fi = 0; fi < 4; ++fi)
                #pragma unroll
                for (int fj = 0; fj < 4; ++fj)
                    acc[fi][fj] = __builtin_amdgcn_mfma_f32_16x16x32_bf16(
                        af[fi], bfr[fj], acc[fi][fj], 0, 0, 0);
        }
        __syncthreads();
    }

    float wsqc[4];
    #pragma unroll
    for (int fj = 0; fj < 4; ++fj)
        wsqc[fj] = wsqv[kt * 128 + wc * 64 + fj * 16 + c15];

    #pragma unroll
    for (int fi = 0; fi < 4; ++fi) {
        float vmx[2][4];
        #pragma unroll
        for (int fjp = 0; fjp < 2; ++fjp) {
            #pragma unroll
            for (int rg = 0; rg < 4; ++rg) {
                float a0 = 2.0f * acc[fi][2 * fjp][rg]     - wsqc[2 * fjp];
                float a1 = 2.0f * acc[fi][2 * fjp + 1][rg] - wsqc[2 * fjp + 1];
                float v = fmaxf(a0, a1);
                v = fmaxf(v, __shfl_xor(v, 1));
                v = fmaxf(v, __shfl_xor(v, 2));
                v = fmaxf(v, __shfl_xor(v, 4));
                v = fmaxf(v, __shfl_xor(v, 8));
                vmx[fjp][rg] = v;
            }
        }
        if (c15 < 4) {
            int row = wr * 64 + fi * 16 + q * 4 + c15;
            rowbuf[row][wc * 2 + 0] = vmx[0][c15];
            rowbuf[row][wc * 2 + 1] = vmx[1][c15];
        }
    }
    __syncthreads();
    {
        int row = tid >> 1, half = tid & 1;
        float2 v2 = make_float2(rowbuf[row][half * 2], rowbuf[row][half * 2 + 1]);
        *(float2*)(cmax + (size_t)(mt * 128 + row) * 256 + kt * 4 + half * 2) = v2;
    }
}

// ---------------------------------------------------------------------------
// Kernel 5: candidate build, bucketed by group. One wave per token.
__global__ __launch_bounds__(256) void cand_kernel(const float* __restrict__ cmax,
                                                   unsigned int* __restrict__ gseg,
                                                   int* __restrict__ gcnt,
                                                   unsigned long long* __restrict__ packed,
                                                   int* __restrict__ nflag,
                                                   int* __restrict__ oflow) {
    const int t = threadIdx.x, wv = t >> 6, lane = t & 63;
    const int n = blockIdx.x * 4 + wv;
    float4 c4 = *(const float4*)(cmax + (size_t)n * 256 + lane * 4);
    float lm = fmaxf(fmaxf(c4.x, c4.y), fmaxf(c4.z, c4.w));
    #pragma unroll
    for (int off = 1; off <= 32; off <<= 1) lm = fmaxf(lm, __shfl_xor(lm, off));
    const float thresh = lm - MARGIN;
    if (lane == 0) { packed[n] = 0ull; nflag[n] = 0; }
    float g4[4] = {c4.x, c4.y, c4.z, c4.w};
    #pragma unroll
    for (int j = 0; j < 4; ++j) {
        int g = lane * 4 + j;
        if (g4[j] >= thresh) {
            int pos = atomicAdd(&gcnt[g], 1);
            if (pos < GCAP) gseg[(size_t)g * GCAP + pos] = (unsigned int)n;
            else { nflag[n] = 1; atomicAdd(oflow, 1); }
        }
    }
}

// ---------------------------------------------------------------------------
// Kernel 6: group-centric exact fp32 rescore. One block per group; W group
// (32 codes x 256 d = 32 KB) staged in LDS once; lane = code.
// DO NOT CHANGE THE DOT SUMMATION ORDER (same knife-edge contract as wsq).
__global__ __launch_bounds__(256) void rescore_kernel(const float* __restrict__ zn,
                                                      const float* __restrict__ W,
                                                      const float* __restrict__ wsqv,
                                                      const float* __restrict__ znsq,
                                                      const unsigned int* __restrict__ gseg,
                                                      const int* __restrict__ gcnt,
                                                      unsigned long long* __restrict__ packed) {
    __shared__ float sW[32 * 260];       // stride 260: spread banks
    __shared__ float znr[4][2][256];     // per-wave, per-half token rows

    const int t = threadIdx.x;
    const int g = blockIdx.x;
    int cnt = gcnt[g]; if (cnt > GCAP) cnt = GCAP;
    if (cnt == 0) return;

    {   // stage W group (contiguous 32 KB chunk of W)
        int c = t >> 3, i = t & 7;
        const float4* src = (const float4*)(W + (size_t)g * 8192 + c * 256 + i * 32);
        #pragma unroll
        for (int j = 0; j < 8; ++j)
            *(float4*)(sW + c * 260 + i * 32 + j * 4) = src[j];
    }
    __syncthreads();

    const int wv = t >> 6, lane = t & 63;
    const int h = lane >> 5, c = lane & 31;
    const int k = g * 32 + c;
    const float wq = wsqv[k];
    const float4* wrow = (const float4*)(sW + c * 260);

    for (int base = wv * 2; base < cnt; base += 8) {
        int idx = base + h; if (idx >= cnt) idx = base;
        int n = (int)gseg[(size_t)g * GCAP + idx];
        *(float4*)(&znr[wv][h][c * 8])     = *(const float4*)(zn + (size_t)n * DD + c * 8);
        *(float4*)(&znr[wv][h][c * 8 + 4]) = *(const float4*)(zn + (size_t)n * DD + c * 8 + 4);
        float d = 0.f;
        #pragma unroll
        for (int j = 0; j < 64; ++j) {
            float4 wv4 = wrow[j];
            float4 zv  = *(const float4*)(&znr[wv][h][j * 4]);
            d += wv4.x * zv.x + wv4.y * zv.y + wv4.z * zv.z + wv4.w * zv.w;
        }
        float s = (-znsq[n] - wq) + 2.0f * d;
        unsigned long long key = pack_key(s, k);
        #pragma unroll
        for (int off = 1; off <= 16; off <<= 1) {
            unsigned long long ok = __shfl_xor(key, off);
            if (ok > key) key = ok;
        }
        if (c == 0) atomicMax(packed + n, key);
    }
}

// ---------------------------------------------------------------------------
// Kernel 7: fullscan fallback for overflow-flagged tokens (early-exit normally).
__global__ __launch_bounds__(256) void fullscan_kernel(const float* __restrict__ zn,
                                                       const float* __restrict__ W,
                                                       const float* __restrict__ wsqv,
                                                       const float* __restrict__ znsq,
                                                       const int* __restrict__ nflag,
                                                       const int* __restrict__ oflow,
                                                       unsigned long long* __restrict__ packed) {
    if (*oflow == 0) return;
    const int t = threadIdx.x, wv = t >> 6, lane = t & 63;
    const int code = lane >> 1, part = lane & 1;
    for (int n = blockIdx.x * 4 + wv; n < NN; n += gridDim.x * 4) {
        if (!nflag[n]) continue;
        float zsq = znsq[n];
        unsigned long long best = 0ull;
        for (int gg = 0; gg < 256; ++gg) {
            int k = gg * 32 + code;
            const float4* wrp = (const float4*)(W + (size_t)k * DD + part * 128);
            const float4* zrp = (const float4*)(zn + (size_t)n * DD + part * 128);
            float d = 0.f;
            #pragma unroll
            for (int jj = 0; jj < 32; ++jj) {
                float4 a = zrp[jj], b = wrp[jj];
                d += a.x * b.x + a.y * b.y + a.z * b.z + a.w * b.w;
            }
            d += __shfl_xor(d, 1);
            unsigned long long key = pack_key((-zsq - wsqv[k]) + 2.0f * d, k);
            if (key > best) best = key;
        }
        #pragma unroll
        for (int off = 1; off <= 32; off <<= 1) {
            unsigned long long ok = __shfl_xor(best, off);
            if (ok > best) best = ok;
        }
        if (lane == 0) atomicMax(packed + n, best);
    }
}

// ---------------------------------------------------------------------------
// Kernel 8: fused finalize + gather. Decodes packed -> idx/loss, then gathers
// z_q coalesced over hw.
__global__ __launch_bounds__(256) void gatherfin_kernel(const float* __restrict__ W,
                                                        const unsigned long long* __restrict__ packed,
                                                        float* __restrict__ idxf,
                                                        float* __restrict__ partials,
                                                        float* __restrict__ zq) {
    __shared__ int sbk[64];
    const int t   = threadIdx.x;
    const int b   = blockIdx.x >> 4;
    const int hw0 = (blockIdx.x & 15) * 64;
    if (t < 64) {
        int n = b * HW + hw0 + t;
        unsigned long long key = packed[n];
        int k = (int)((~(unsigned int)key) & 0x3FFFu);
        unsigned int o = (unsigned int)(key >> 32);
        unsigned int bits = (o & 0x80000000u) ? (o & 0x7FFFFFFFu) : ~o;
        float s = __uint_as_float(bits);
        sbk[t] = k;
        idxf[n] = (float)k;
        float cc = -s;
        #pragma unroll
        for (int off = 32; off; off >>= 1) cc += __shfl_down(cc, off);
        if (t == 0) partials[blockIdx.x] = cc;
    }
    __syncthreads();
    const int hw  = t & 63;
    const int c0  = (t >> 6) * 4;
    const int row = sbk[hw];
    #pragma unroll
    for (int cg = 0; cg < 16; ++cg) {
        int c = cg * 16 + c0;
        float4 v = *(const float4*)(W + (size_t)row * DD + c);
        size_t base = ((size_t)(b * CC + c) << 10) + hw0 + hw;
        zq[base]        = v.x;
        zq[base + 1024] = v.y;
        zq[base + 2048] = v.z;
        zq[base + 3072] = v.w;
    }
}

// ---------------------------------------------------------------------------
// Kernel 9: final loss = BETA * sum(256 partials) / (N*D)
__global__ __launch_bounds__(256) void loss_final_kernel(const float* __restrict__ partials,
                                                         float* __restrict__ out_loss) {
    __shared__ float wsum[4];
    const int t = threadIdx.x;
    float v = partials[t];
    #pragma unroll
    for (int off = 32; off; off >>= 1) v += __shfl_down(v, off);
    if ((t & 63) == 0) wsum[t >> 6] = v;
    __syncthreads();
    if (t == 0) {
        float tot = wsum[0] + wsum[1] + wsum[2] + wsum[3];
        *out_loss = 0.25f * (tot / (float)ZQ_SIZE);
    }
}

// ---------------------------------------------------------------------------
extern "C" void kernel_launch(void* const* d_in, const int* in_sizes, int n_in,
                              void* d_out, int out_size, void* d_ws, size_t ws_size,
                              hipStream_t stream) {
    const float* z = (const float*)d_in[0];   // [16,256,32,32]
    const float* W = (const float*)d_in[1];   // [8192,256]

    float* out   = (float*)d_out;
    float* zq    = out;                 // 4194304
    float* loss  = out + ZQ_SIZE;       // 1
    float* idxf  = out + ZQ_SIZE + 1;   // 16384 (idx as float)

    float* ws       = (float*)d_ws;
    float* zn       = ws;                         // 16 MB
    float* znsq     = zn + (size_t)NN * DD;       // 16384 f
    float* wsqv     = znsq + NN;                  // 8192 f
    float* partials = wsqv + KK;                  // 256 f
    int*   gcnt     = (int*)(partials + 256);     // 256 i
    int*   oflow    = gcnt + 256;                 // 1 (pad 64)
    int*   nflag    = oflow + 64;                 // 16384 i
    unsigned short* zb = (unsigned short*)(nflag + NN);       // 8 MB
    unsigned short* wb = zb + (size_t)NN * DD;                // 4 MB
    float* cmax     = (float*)(wb + (size_t)KK * DD);         // 16 MB
    unsigned int* gseg = (unsigned int*)(cmax + (size_t)NN * 256); // 8 MB
    unsigned long long* packed = (unsigned long long*)(gseg + (size_t)256 * GCAP); // 128 KB

    wsq_kernel       <<<KK / 4, 256, 0, stream>>>(W, wsqv, gcnt, oflow);
    normalize_kernel <<<BB * 16, 256, 0, stream>>>(z, zn, znsq, zb);
    wb_convert_kernel<<<KK * DD / 8 / 256, 256, 0, stream>>>(W, wb);
    score_kernel     <<<(NN / 128) * (KK / 128), 256, 0, stream>>>(zb, wb, wsqv, cmax);
    cand_kernel      <<<NN / 4, 256, 0, stream>>>(cmax, gseg, gcnt, packed, nflag, oflow);
    rescore_kernel   <<<256, 256, 0, stream>>>(zn, W, wsqv, znsq, gseg, gcnt, packed);
    fullscan_kernel  <<<64, 256, 0, stream>>>(zn, W, wsqv, znsq, nflag, oflow, packed);
    gatherfin_kernel <<<BB * 16, 256, 0, stream>>>(W, packed, idxf, partials, zq);
    loss_final_kernel<<<1, 256, 0, stream>>>(partials, loss);
}

// Round 8
// 232.444 us; speedup vs baseline: 3.0076x; 1.2486x over previous
//
#include <hip/hip_runtime.h>
#include <math.h>

// Problem constants
#define BB   16
#define CC   256
#define HW   1024          // 32*32
#define NN   16384         // BB*HW tokens
#define DD   256           // dim
#define KK   8192          // codes
#define ZQ_SIZE 4194304    // 16*256*1024
#define MARGIN 0.017f      // rigorous bf16-score error envelope (bound 0.0156)
#define GCAP 8192          // per-group candidate-token capacity (overflow -> fullscan)
#define RSPLIT 8           // rescore blocks per group (load-balance)

typedef __attribute__((ext_vector_type(8))) short short8;  // 8 bf16 (4 VGPRs)
typedef __attribute__((ext_vector_type(4))) float f32x4;

static __device__ inline unsigned short f2bf(float x) {
    unsigned int u = __float_as_uint(x);
    unsigned int r = (u + 0x7fff + ((u >> 16) & 1)) >> 16;   // RNE
    return (unsigned short)r;
}

static __device__ inline unsigned long long pack_key(float s, int k) {
    unsigned int bits = __float_as_uint(s);
    unsigned int o = (bits & 0x80000000u) ? ~bits : (bits | 0x80000000u);
    return ((unsigned long long)o << 32) | (unsigned int)(~k);
}

// ---------------------------------------------------------------------------
// Kernel 1: wsq (VERBATIM R4 chain — FROZEN: knife-edge fp32 argmax contract;
// R5/R6 reordered this sum and deterministically flipped one token's idx)
// + wb bf16 blob (verbatim body, blocks 0..1023) fused in one W pass.
// Block 0 zeroes gcnt/oflow.
__global__ __launch_bounds__(256) void wsqwb_kernel(const float* __restrict__ W,
                                                    float* __restrict__ wsq,
                                                    unsigned short* __restrict__ wb,
                                                    int* __restrict__ gcnt,
                                                    int* __restrict__ oflow) {
    if (blockIdx.x == 0) {
        gcnt[threadIdx.x] = 0;
        if (threadIdx.x == 0) *oflow = 0;
    }
    {   // --- wsq part: FROZEN summation order (float4 at lane*4, 64-lane tree)
        const int lane = threadIdx.x & 63;
        const int k = blockIdx.x * 4 + (threadIdx.x >> 6);
        float4 v = *(const float4*)(W + (size_t)k * DD + lane * 4);
        float s = v.x * v.x + v.y * v.y + v.z * v.z + v.w * v.w;
        #pragma unroll
        for (int off = 32; off; off >>= 1) s += __shfl_down(s, off);
        if (lane == 0) wsq[k] = s;
    }
    if (blockIdx.x < 1024) {   // --- wb part: verbatim R4 wb_convert body
        const int ch = blockIdx.x * 256 + threadIdx.x;     // 0..262143
        const int c = (ch >> 7) & 7;
        const int r = ch & 127;
        const int kt = ch >> 12, dc = (ch >> 10) & 3;
        const int k = kt * 128 + r;
        const int d0 = dc * 64 + c * 8;
        const float4 v0 = *(const float4*)(W + (size_t)k * DD + d0);
        const float4 v1 = *(const float4*)(W + (size_t)k * DD + d0 + 4);
        uint4 out;
        out.x = (unsigned int)f2bf(v0.x) | ((unsigned int)f2bf(v0.y) << 16);
        out.y = (unsigned int)f2bf(v0.z) | ((unsigned int)f2bf(v0.w) << 16);
        out.z = (unsigned int)f2bf(v1.x) | ((unsigned int)f2bf(v1.y) << 16);
        out.w = (unsigned int)f2bf(v1.z) | ((unsigned int)f2bf(v1.w) << 16);
        *(uint4*)(wb + (size_t)ch * 8) = out;
    }
}

// ---------------------------------------------------------------------------
// Kernel 2: transpose + l2-normalize. Same tile cells / sum order / division
// as the passing R7 version (bit-identical values); only the z-load is
// vectorized to float4 (hw-contiguous).
__global__ __launch_bounds__(256) void normalize_kernel(const float* __restrict__ z,
                                                        float* __restrict__ zn,
                                                        float* __restrict__ znsq,
                                                        unsigned short* __restrict__ zb) {
    __shared__ float tile[64][257];
    __shared__ float s_nrm[64];
    const int t   = threadIdx.x;
    const int b   = blockIdx.x >> 4;
    const int hw0 = (blockIdx.x & 15) * 64;

    #pragma unroll
    for (int cg = 0; cg < 16; ++cg) {
        int c  = cg * 16 + (t >> 4);
        int hw = (t & 15) * 4;
        float4 v = *(const float4*)(z + ((size_t)(b * CC + c) << 10) + hw0 + hw);
        tile[hw + 0][c] = v.x;
        tile[hw + 1][c] = v.y;
        tile[hw + 2][c] = v.z;
        tile[hw + 3][c] = v.w;
    }
    __syncthreads();
    if (t < 64) {
        float s = 0.f;
        #pragma unroll 8
        for (int c = 0; c < 256; ++c) { float v = tile[t][c]; s += v * v; }
        float nrm = sqrtf(s);
        nrm = fmaxf(nrm, 1e-12f);
        s_nrm[t] = nrm;
        znsq[(size_t)b * HW + hw0 + t] = s / (nrm * nrm);
    }
    __syncthreads();
    const int n0 = b * HW + hw0;           // multiple of 64
    for (int r = 0; r < 64; ++r) {
        zn[(size_t)(n0 + r) * DD + t] = tile[r][t] / s_nrm[r];
    }
    const int r    = t & 63;
    const int mt   = n0 >> 7;
    const int rg   = (n0 & 127) + r;
    const float nrm = s_nrm[r];
    #pragma unroll
    for (int loop = 0; loop < 8; ++loop) {
        int comb = loop * 4 + (t >> 6);    // 0..31
        int dc = comb >> 3, c = comb & 7;
        int d0 = dc * 64 + c * 8;
        uint4 out;
        out.x = (unsigned int)f2bf(tile[r][d0 + 0] / nrm) | ((unsigned int)f2bf(tile[r][d0 + 1] / nrm) << 16);
        out.y = (unsigned int)f2bf(tile[r][d0 + 2] / nrm) | ((unsigned int)f2bf(tile[r][d0 + 3] / nrm) << 16);
        out.z = (unsigned int)f2bf(tile[r][d0 + 4] / nrm) | ((unsigned int)f2bf(tile[r][d0 + 5] / nrm) << 16);
        out.w = (unsigned int)f2bf(tile[r][d0 + 6] / nrm) | ((unsigned int)f2bf(tile[r][d0 + 7] / nrm) << 16);
        *(uint4*)(zb + (size_t)(mt * 4 + dc) * 8192 + (size_t)(c * 128 + rg) * 8) = out;
    }
}

// ---------------------------------------------------------------------------
// Kernel 3: MFMA scorer, TRANSPOSED (A=codes M, B=tokens N). C layout:
// col=lane&15=token, row=(lane>>4)*4+reg=code -> a 32-code group max is
// 8 regs in-thread + 2 shfl (over q), vs 128 shfl in the untransposed form.
// cmax only feeds MARGIN-buffered selection; ulp-level ordering differences
// are harmless (exonerated by R6's identical-failure bisect).
__global__ __launch_bounds__(256) void score_kernel(const unsigned short* __restrict__ zb,
                                                    const unsigned short* __restrict__ wb,
                                                    const float* __restrict__ wsqv,
                                                    float* __restrict__ cmax) {
    __shared__ unsigned short sA[8192];   // 16 KB: tokens [8 chunks][128][8]
    __shared__ unsigned short sB[8192];   // 16 KB: codes
    __shared__ float rowbuf[128][4];
    __shared__ __align__(16) float swsq[128];

    const int tid  = threadIdx.x;
    const int w    = tid >> 6;
    const int lane = tid & 63;
    const int wcr  = w >> 1;              // code half (0/1)
    const int wct  = w & 1;               // token half (0/1)
    const int q    = lane >> 4, c15 = lane & 15;
    const int kt   = blockIdx.x & 63;
    const int mt   = blockIdx.x >> 6;

    if (tid < 128) swsq[tid] = wsqv[kt * 128 + tid];

    f32x4 acc[4][4];                      // [code tile][token tile]
    #pragma unroll
    for (int fi = 0; fi < 4; ++fi)
        #pragma unroll
        for (int fj = 0; fj < 4; ++fj)
            acc[fi][fj] = (f32x4){0.f, 0.f, 0.f, 0.f};

    for (int dc = 0; dc < 4; ++dc) {
        const unsigned short* gA = zb + (size_t)(mt * 4 + dc) * 8192;
        const unsigned short* gB = wb + (size_t)(kt * 4 + dc) * 8192;
        #pragma unroll
        for (int i = 0; i < 4; ++i) {
            int eo = ((w * 4 + i) << 9);
            __builtin_amdgcn_global_load_lds(
                (const __attribute__((address_space(1))) void*)(gA + eo + lane * 8),
                (__attribute__((address_space(3))) void*)(sA + eo), 16, 0, 0);
            __builtin_amdgcn_global_load_lds(
                (const __attribute__((address_space(1))) void*)(gB + eo + lane * 8),
                (__attribute__((address_space(3))) void*)(sB + eo), 16, 0, 0);
        }
        __syncthreads();
        #pragma unroll
        for (int ks = 0; ks < 2; ++ks) {
            short8 tfr[4], cfr[4];
            const int ca = (ks * 4 + q) * 128;
            #pragma unroll
            for (int f = 0; f < 4; ++f) {
                tfr[f] = *(const short8*)(sA + (size_t)(ca + wct * 64 + f * 16 + c15) * 8);
                cfr[f] = *(const short8*)(sB + (size_t)(ca + wcr * 64 + f * 16 + c15) * 8);
            }
            #pragma unroll
            for (int fi = 0; fi < 4; ++fi)
                #pragma unroll
                for (int fj = 0; fj < 4; ++fj)
                    acc[fi][fj] = __builtin_amdgcn_mfma_f32_16x16x32_bf16(
                        cfr[fi], tfr[fj], acc[fi][fj], 0, 0, 0);
        }
        __syncthreads();
    }

    // wsq for this lane's 16 code rows (4 per code tile)
    f32x4 wq4[4];
    #pragma unroll
    for (int fi = 0; fi < 4; ++fi)
        wq4[fi] = *(const f32x4*)(&swsq[wcr * 64 + fi * 16 + q * 4]);

    #pragma unroll
    for (int fj = 0; fj < 4; ++fj) {
        float g[2];
        #pragma unroll
        for (int p = 0; p < 2; ++p) {
            float vm = -INFINITY;
            #pragma unroll
            for (int f2 = 0; f2 < 2; ++f2) {
                int fi = p * 2 + f2;
                #pragma unroll
                for (int rg = 0; rg < 4; ++rg)
                    vm = fmaxf(vm, 2.0f * acc[fi][fj][rg] - wq4[fi][rg]);
            }
            vm = fmaxf(vm, __shfl_xor(vm, 16));
            vm = fmaxf(vm, __shfl_xor(vm, 32));
            g[p] = vm;
        }
        if (q == 0) {
            int row = wct * 64 + fj * 16 + c15;
            rowbuf[row][wcr * 2 + 0] = g[0];
            rowbuf[row][wcr * 2 + 1] = g[1];
        }
    }
    __syncthreads();
    {
        int row = tid >> 1, half = tid & 1;
        float2 v2 = make_float2(rowbuf[row][half * 2], rowbuf[row][half * 2 + 1]);
        *(float2*)(cmax + (size_t)(mt * 128 + row) * 256 + kt * 4 + half * 2) = v2;
    }
}

// ---------------------------------------------------------------------------
// Kernel 4: candidate build, bucketed by group. One wave per token.
__global__ __launch_bounds__(256) void cand_kernel(const float* __restrict__ cmax,
                                                   unsigned int* __restrict__ gseg,
                                                   int* __restrict__ gcnt,
                                                   unsigned long long* __restrict__ packed,
                                                   int* __restrict__ nflag,
                                                   int* __restrict__ oflow) {
    const int t = threadIdx.x, wv = t >> 6, lane = t & 63;
    const int n = blockIdx.x * 4 + wv;
    float4 c4 = *(const float4*)(cmax + (size_t)n * 256 + lane * 4);
    float lm = fmaxf(fmaxf(c4.x, c4.y), fmaxf(c4.z, c4.w));
    #pragma unroll
    for (int off = 1; off <= 32; off <<= 1) lm = fmaxf(lm, __shfl_xor(lm, off));
    const float thresh = lm - MARGIN;
    if (lane == 0) { packed[n] = 0ull; nflag[n] = 0; }
    float g4[4] = {c4.x, c4.y, c4.z, c4.w};
    #pragma unroll
    for (int j = 0; j < 4; ++j) {
        int g = lane * 4 + j;
        if (g4[j] >= thresh) {
            int pos = atomicAdd(&gcnt[g], 1);
            if (pos < GCAP) gseg[(size_t)g * GCAP + pos] = (unsigned int)n;
            else { nflag[n] = 1; atomicAdd(oflow, 1); }
        }
    }
}

// ---------------------------------------------------------------------------
// Kernel 5: group-centric exact fp32 rescore, 8 blocks per group
// (load-balance the big groups). Per-token fp32 chain is FROZEN (same dot
// order as R4/R7); atomicMax merge is order-independent, so the token->block
// assignment change cannot alter results.
__global__ __launch_bounds__(256) void rescore_kernel(const float* __restrict__ zn,
                                                      const float* __restrict__ W,
                                                      const float* __restrict__ wsqv,
                                                      const float* __restrict__ znsq,
                                                      const unsigned int* __restrict__ gseg,
                                                      const int* __restrict__ gcnt,
                                                      unsigned long long* __restrict__ packed) {
    __shared__ float sW[32 * 260];       // stride 260: spread banks
    __shared__ float znr[4][2][256];     // per-wave, per-half token rows

    const int t = threadIdx.x;
    const int g   = blockIdx.x >> 3;
    const int sub = blockIdx.x & 7;
    int cnt = gcnt[g]; if (cnt > GCAP) cnt = GCAP;
    if (cnt <= sub * 8) return;          // this sub-block has no tokens

    {   // stage W group (contiguous 32 KB chunk of W)
        int c = t >> 3, i = t & 7;
        const float4* src = (const float4*)(W + (size_t)g * 8192 + c * 256 + i * 32);
        #pragma unroll
        for (int j = 0; j < 8; ++j)
            *(float4*)(sW + c * 260 + i * 32 + j * 4) = src[j];
    }
    __syncthreads();

    const int wv = t >> 6, lane = t & 63;
    const int h = lane >> 5, c = lane & 31;
    const int k = g * 32 + c;
    const float wq = wsqv[k];
    const float4* wrow = (const float4*)(sW + c * 260);

    for (int base = (sub * 4 + wv) * 2; base < cnt; base += RSPLIT * 8) {
        int idx = base + h; if (idx >= cnt) idx = base;
        int n = (int)gseg[(size_t)g * GCAP + idx];
        *(float4*)(&znr[wv][h][c * 8])     = *(const float4*)(zn + (size_t)n * DD + c * 8);
        *(float4*)(&znr[wv][h][c * 8 + 4]) = *(const float4*)(zn + (size_t)n * DD + c * 8 + 4);
        float d = 0.f;
        #pragma unroll
        for (int j = 0; j < 64; ++j) {
            float4 wv4 = wrow[j];
            float4 zv  = *(const float4*)(&znr[wv][h][j * 4]);
            d += wv4.x * zv.x + wv4.y * zv.y + wv4.z * zv.z + wv4.w * zv.w;
        }
        float s = (-znsq[n] - wq) + 2.0f * d;
        unsigned long long key = pack_key(s, k);
        #pragma unroll
        for (int off = 1; off <= 16; off <<= 1) {
            unsigned long long ok = __shfl_xor(key, off);
            if (ok > key) key = ok;
        }
        if (c == 0) atomicMax(packed + n, key);
    }
}

// ---------------------------------------------------------------------------
// Kernel 6: fullscan fallback for overflow-flagged tokens (early-exit normally).
__global__ __launch_bounds__(256) void fullscan_kernel(const float* __restrict__ zn,
                                                       const float* __restrict__ W,
                                                       const float* __restrict__ wsqv,
                                                       const float* __restrict__ znsq,
                                                       const int* __restrict__ nflag,
                                                       const int* __restrict__ oflow,
                                                       unsigned long long* __restrict__ packed) {
    if (*oflow == 0) return;
    const int t = threadIdx.x, wv = t >> 6, lane = t & 63;
    const int code = lane >> 1, part = lane & 1;
    for (int n = blockIdx.x * 4 + wv; n < NN; n += gridDim.x * 4) {
        if (!nflag[n]) continue;
        float zsq = znsq[n];
        unsigned long long best = 0ull;
        for (int gg = 0; gg < 256; ++gg) {
            int k = gg * 32 + code;
            const float4* wrp = (const float4*)(W + (size_t)k * DD + part * 128);
            const float4* zrp = (const float4*)(zn + (size_t)n * DD + part * 128);
            float d = 0.f;
            #pragma unroll
            for (int jj = 0; jj < 32; ++jj) {
                float4 a = zrp[jj], b = wrp[jj];
                d += a.x * b.x + a.y * b.y + a.z * b.z + a.w * b.w;
            }
            d += __shfl_xor(d, 1);
            unsigned long long key = pack_key((-zsq - wsqv[k]) + 2.0f * d, k);
            if (key > best) best = key;
        }
        #pragma unroll
        for (int off = 1; off <= 32; off <<= 1) {
            unsigned long long ok = __shfl_xor(best, off);
            if (ok > best) best = ok;
        }
        if (lane == 0) atomicMax(packed + n, best);
    }
}

// ---------------------------------------------------------------------------
// Kernel 7: fused finalize + gather. Decodes packed -> idx/loss, then gathers
// z_q coalesced over hw.
__global__ __launch_bounds__(256) void gatherfin_kernel(const float* __restrict__ W,
                                                        const unsigned long long* __restrict__ packed,
                                                        float* __restrict__ idxf,
                                                        float* __restrict__ partials,
                                                        float* __restrict__ zq) {
    __shared__ int sbk[64];
    const int t   = threadIdx.x;
    const int b   = blockIdx.x >> 4;
    const int hw0 = (blockIdx.x & 15) * 64;
    if (t < 64) {
        int n = b * HW + hw0 + t;
        unsigned long long key = packed[n];
        int k = (int)((~(unsigned int)key) & 0x3FFFu);
        unsigned int o = (unsigned int)(key >> 32);
        unsigned int bits = (o & 0x80000000u) ? (o & 0x7FFFFFFFu) : ~o;
        float s = __uint_as_float(bits);
        sbk[t] = k;
        idxf[n] = (float)k;
        float cc = -s;
        #pragma unroll
        for (int off = 32; off; off >>= 1) cc += __shfl_down(cc, off);
        if (t == 0) partials[blockIdx.x] = cc;
    }
    __syncthreads();
    const int hw  = t & 63;
    const int c0  = (t >> 6) * 4;
    const int row = sbk[hw];
    #pragma unroll
    for (int cg = 0; cg < 16; ++cg) {
        int c = cg * 16 + c0;
        float4 v = *(const float4*)(W + (size_t)row * DD + c);
        size_t base = ((size_t)(b * CC + c) << 10) + hw0 + hw;
        zq[base]        = v.x;
        zq[base + 1024] = v.y;
        zq[base + 2048] = v.z;
        zq[base + 3072] = v.w;
    }
}

// ---------------------------------------------------------------------------
// Kernel 8: final loss = BETA * sum(256 partials) / (N*D)
__global__ __launch_bounds__(256) void loss_final_kernel(const float* __restrict__ partials,
                                                         float* __restrict__ out_loss) {
    __shared__ float wsum[4];
    const int t = threadIdx.x;
    float v = partials[t];
    #pragma unroll
    for (int off = 32; off; off >>= 1) v += __shfl_down(v, off);
    if ((t & 63) == 0) wsum[t >> 6] = v;
    __syncthreads();
    if (t == 0) {
        float tot = wsum[0] + wsum[1] + wsum[2] + wsum[3];
        *out_loss = 0.25f * (tot / (float)ZQ_SIZE);
    }
}

// ---------------------------------------------------------------------------
extern "C" void kernel_launch(void* const* d_in, const int* in_sizes, int n_in,
                              void* d_out, int out_size, void* d_ws, size_t ws_size,
                              hipStream_t stream) {
    const float* z = (const float*)d_in[0];   // [16,256,32,32]
    const float* W = (const float*)d_in[1];   // [8192,256]

    float* out   = (float*)d_out;
    float* zq    = out;                 // 4194304
    float* loss  = out + ZQ_SIZE;       // 1
    float* idxf  = out + ZQ_SIZE + 1;   // 16384 (idx as float)

    float* ws       = (float*)d_ws;
    float* zn       = ws;                         // 16 MB
    float* znsq     = zn + (size_t)NN * DD;       // 16384 f
    float* wsqv     = znsq + NN;                  // 8192 f
    float* partials = wsqv + KK;                  // 256 f
    int*   gcnt     = (int*)(partials + 256);     // 256 i
    int*   oflow    = gcnt + 256;                 // 1 (pad 64)
    int*   nflag    = oflow + 64;                 // 16384 i
    unsigned short* zb = (unsigned short*)(nflag + NN);       // 8 MB
    unsigned short* wb = zb + (size_t)NN * DD;                // 4 MB
    float* cmax     = (float*)(wb + (size_t)KK * DD);         // 16 MB
    unsigned int* gseg = (unsigned int*)(cmax + (size_t)NN * 256); // 8 MB
    unsigned long long* packed = (unsigned long long*)(gseg + (size_t)256 * GCAP); // 128 KB

    wsqwb_kernel     <<<KK / 4, 256, 0, stream>>>(W, wsqv, wb, gcnt, oflow);
    normalize_kernel <<<BB * 16, 256, 0, stream>>>(z, zn, znsq, zb);
    score_kernel     <<<(NN / 128) * (KK / 128), 256, 0, stream>>>(zb, wb, wsqv, cmax);
    cand_kernel      <<<NN / 4, 256, 0, stream>>>(cmax, gseg, gcnt, packed, nflag, oflow);
    rescore_kernel   <<<256 * RSPLIT, 256, 0, stream>>>(zn, W, wsqv, znsq, gseg, gcnt, packed);
    fullscan_kernel  <<<64, 256, 0, stream>>>(zn, W, wsqv, znsq, nflag, oflow, packed);
    gatherfin_kernel <<<BB * 16, 256, 0, stream>>>(W, packed, idxf, partials, zq);
    loss_final_kernel<<<1, 256, 0, stream>>>(partials, loss);
}